// Round 7
// baseline (3244.651 us; speedup 1.0000x reference)
//
#include <hip/hip_runtime.h>
#include <hip/hip_bf16.h>

#define EMB 768
#define HID 3072
#define HID2 6144
#define NE 8
#define TOK 16384    // B*N = 8*2048
#define SLOTS 32768  // TOK * top-2
#define SLACK 256    // tail-read slack rows (M-tile 256 may overrun by 255)
#define MAXTILES 136 // max active M-tiles: 128 + (NE-1) partials

typedef __attribute__((ext_vector_type(8))) short bf16x8;
typedef __attribute__((ext_vector_type(4))) float f32x4;
typedef __attribute__((ext_vector_type(16))) float f32x16;

__device__ __forceinline__ unsigned short bfbits(float f) {
  __hip_bfloat16 h = __float2bfloat16(f);
  return __builtin_bit_cast(unsigned short, h);
}

// ---------------- init / gating / routing ----------------

__global__ void k_init(int* counts, int* fill) {
  if (threadIdx.x < NE) { counts[threadIdx.x] = 0; fill[threadIdx.x] = 0; }
}

__global__ __launch_bounds__(256) void k_gating(
    const float* __restrict__ x, const float* __restrict__ Wg,
    const float* __restrict__ bg, int* __restrict__ eidx,
    float* __restrict__ gates, int* __restrict__ counts)
{
  const int wave = threadIdx.x >> 6, lane = threadIdx.x & 63;
  const int t = blockIdx.x * 4 + wave;
  const float* xr = x + (size_t)t * EMB;
  float p[NE];
#pragma unroll
  for (int e = 0; e < NE; ++e) p[e] = 0.f;
  for (int k = lane; k < EMB; k += 64) {
    const float xv = xr[k];
    const float* wr = Wg + (size_t)k * NE;
#pragma unroll
    for (int e = 0; e < NE; ++e) p[e] += xv * wr[e];
  }
#pragma unroll
  for (int e = 0; e < NE; ++e) {
#pragma unroll
    for (int o = 32; o > 0; o >>= 1) p[e] += __shfl_xor(p[e], o);
    p[e] += bg[e];
  }
  float v0 = -1e30f, v1 = -1e30f; int i0 = 0, i1 = 0;
#pragma unroll
  for (int e = 0; e < NE; ++e) {
    const float v = p[e];
    if (v > v0)      { v1 = v0; i1 = i0; v0 = v; i0 = e; }
    else if (v > v1) { v1 = v;  i1 = e; }
  }
  const float ex = expf(v1 - v0);
  const float g0 = 1.f / (1.f + ex);
  const float g1 = 1.f - g0;
  if (lane == 0) {
    eidx[2*t] = i0; eidx[2*t+1] = i1;
    gates[2*t] = g0; gates[2*t+1] = g1;
    atomicAdd(&counts[i0], 1);
    atomicAdd(&counts[i1], 1);
  }
}

// offsets + compact (expert, m-tile) map so GEMM grid has ~no empty blocks
__global__ void k_offsets(const int* __restrict__ counts, int* __restrict__ offsets,
                          int* __restrict__ tmap)
{
  offsets[0] = 0;
  int idx = 0;
  for (int e = 0; e < NE; ++e) {
    offsets[e+1] = offsets[e] + counts[e];
    const int nt = (counts[e] + 255) >> 8;
    for (int i = 0; i < nt; ++i) tmap[idx++] = (e << 16) | i;
  }
  for (; idx < MAXTILES; ++idx) tmap[idx] = -1;
}

__global__ void k_route(const int* __restrict__ eidx, int* __restrict__ fill,
                        const int* __restrict__ offsets, int* __restrict__ route_tok,
                        int* __restrict__ slot_of)
{
  const int t = blockIdx.x * 256 + threadIdx.x;
  if (t >= TOK) return;
#pragma unroll
  for (int k = 0; k < 2; ++k) {
    const int e = eidx[2*t + k];
    const int pos = atomicAdd(&fill[e], 1);
    const int slot = offsets[e] + pos;
    route_tok[slot] = t;
    slot_of[2*t + k] = slot;
  }
}

__global__ void k_gather(const float* __restrict__ x, const int* __restrict__ route_tok,
                         __hip_bfloat16* __restrict__ xg)
{
  const int s = blockIdx.x;
  const int t = route_tok[s];
  const float4 v = ((const float4*)(x + (size_t)t * EMB))[threadIdx.x];
  ushort4 u;
  u.x = bfbits(v.x); u.y = bfbits(v.y); u.z = bfbits(v.z); u.w = bfbits(v.w);
  *(ushort4*)((unsigned short*)xg + (size_t)s * EMB + threadIdx.x * 4) = u;
}

// fp32 [K,N] -> bf16 [N,K]  (per expert, LDS-tiled transpose, ushort2 writes)
__global__ void k_transpose(const float* __restrict__ W, __hip_bfloat16* __restrict__ Wt,
                            int K, int N)
{
  __shared__ float tile[64][33];   // [k][n]
  const int e = blockIdx.z;
  const float* Wp = W + (size_t)e * K * N;
  __hip_bfloat16* Wtp = Wt + (size_t)e * K * N;
  const int n0 = blockIdx.x * 32, k0 = blockIdx.y * 64;
  for (int r = threadIdx.y; r < 64; r += 8)
    tile[r][threadIdx.x] = Wp[(size_t)(k0 + r) * N + n0 + threadIdx.x];
  __syncthreads();
  // write: row n0+r, thread tx covers k-pair (k0+2tx, k0+2tx+1)
  for (int r = threadIdx.y; r < 32; r += 8) {
    ushort2 u;
    u.x = bfbits(tile[2 * threadIdx.x][r]);
    u.y = bfbits(tile[2 * threadIdx.x + 1][r]);
    *(ushort2*)((unsigned short*)Wtp + (size_t)(n0 + r) * K + k0 + 2 * threadIdx.x) = u;
  }
}

// -------- 256x256 MFMA GEMM (32x32x16), K-half pipeline, 2 barriers/K-tile --
// A: bf16 [slots, K] (per-expert segments); Bt: bf16 [NE, N, K].
// BM=BN=256, BK=64, 8 waves (2M x 4N), per-wave 128x64 C via 4x2 frags of
// 32x32, acc = 4x2 f32x16.  LDS 128 KiB = 2 slots x 64KB;
// slot = [A-klo|A-khi|B-klo|B-khi] 16KB halves (half = 256r/128r x 32 k, 64B rows).
// Swizzle (conflict-free, R4/R6-verified): 16B-slot index ^= (row>>1)&3,
// on global SOURCE (linear global_load_lds dest) + ds_read addr.
// Fragment layout 32x32x16 (family pattern of the verified 16x16x32):
//   A: row=lane&31, k = (lane>>5)*8 + j ; B: col=lane&31, same k.
//   C/D: col=lane&31, row=(reg&3)+8*(reg>>2)+4*(lane>>5)  [m74/m101-verified]
// Sync per K-tile (R6-identical): 2x { 12 ds_read + 4 gload_lds(t+1->slot^1)
// + 16 MFMA unpinned; vmcnt(4); s_barrier }.

#define BARRIER() asm volatile("s_barrier" ::: "memory")

template<bool GELU, bool OUTBF>
__global__ __launch_bounds__(512) void ffn_gemm8(
    const __hip_bfloat16* __restrict__ A,
    const __hip_bfloat16* __restrict__ Bt,
    const float* __restrict__ bias,
    void* __restrict__ Cout,
    const int* __restrict__ counts,
    const int* __restrict__ offsets,
    const int* __restrict__ tmap,
    int K, int N)
{
  const int me = tmap[blockIdx.y];
  if (me < 0) return;
  const int e  = me >> 16;
  const int m0 = (me & 0xffff) << 8;
  const int cnt = counts[e];
  const int seg = offsets[e];
  const int n0 = blockIdx.x * 256;

  __shared__ char lds[131072];

  const int tid = threadIdx.x;
  const int wave = tid >> 6, lane = tid & 63;
  const int wm = wave >> 2, wn = wave & 3;

  const size_t KB = (size_t)K * 2;           // global row stride bytes
  const char* Ag = (const char*)(A + (size_t)(seg + m0) * K);
  const char* Bg = (const char*)(Bt + (size_t)e * N * K + (size_t)n0 * K);

  // staging: one half = 256 rows x 64B = 2 gloads x 512thr x 16B
  const int s_r  = tid >> 2;                                    // 0..127
  const int s_cb = ((tid & 3) * 16) ^ (((s_r >> 1) & 3) << 4);  // src pre-swizzle

  auto stage_half = [&](const char* gbase, int kbyte, int ldsoff) {
    const char* s = gbase + (size_t)s_r * KB + kbyte + s_cb;
    __builtin_amdgcn_global_load_lds(
        (const __attribute__((address_space(1))) void*)s,
        (__attribute__((address_space(3))) void*)(lds + ldsoff + tid * 16), 16, 0, 0);
    __builtin_amdgcn_global_load_lds(
        (const __attribute__((address_space(1))) void*)(s + 128 * KB),
        (__attribute__((address_space(3))) void*)(lds + ldsoff + 8192 + tid * 16), 16, 0, 0);
  };

  // fragment read offsets: row = base + fr5; 16B-slot = (kf*2 + s5) ^ ((fr5>>1)&3)
  const int fr5 = lane & 31;
  const int s5  = lane >> 5;
  const int xr5 = (fr5 >> 1) & 3;
  const int kp0 = ((0 + s5) ^ xr5) << 4;    // kf=0 slot byte
  const int kp1 = ((2 + s5) ^ xr5) << 4;    // kf=1 slot byte
  const int arow = (wm * 128 + fr5) * 64;            // + mf*2048, within A-half
  const int brow = 32768 + (wn * 64 + fr5) * 64;     // + nf*2048, within B-half

  f32x16 acc[4][2];
#pragma unroll
  for (int i = 0; i < 4; ++i)
#pragma unroll
    for (int j = 0; j < 2; ++j)
#pragma unroll
      for (int r = 0; r < 16; ++r)
        acc[i][j][r] = 0.f;

  const int KT = K >> 6;

  // ---- prologue: tile0's 4 halves -> slot0, in deadline order
  stage_half(Ag, 0, 0);          // A-klo
  stage_half(Bg, 0, 32768);      // B-klo
  stage_half(Ag, 64, 16384);     // A-khi
  stage_half(Bg, 64, 49152);     // B-khi
  asm volatile("s_waitcnt vmcnt(4)" ::: "memory");   // klo pair ready
  BARRIER();

  bf16x8 a[4][2], b[2][2];

  for (int kt = 0; kt < KT; ++kt) {
    const int sb  = (kt & 1) * 65536;
    const int sl1 = sb ^ 65536;
    const int kbN = (kt + 1 < KT ? kt + 1 : KT - 1) * 128;

    // ---- half 0 (k 0..31): read klo frags, stage klo(t+1), 16 MFMA — unpinned
#pragma unroll
    for (int m = 0; m < 4; ++m) {
      a[m][0] = *(const bf16x8*)(lds + sb + arow + m * 2048 + kp0);
      a[m][1] = *(const bf16x8*)(lds + sb + arow + m * 2048 + kp1);
    }
#pragma unroll
    for (int n = 0; n < 2; ++n) {
      b[n][0] = *(const bf16x8*)(lds + sb + brow + n * 2048 + kp0);
      b[n][1] = *(const bf16x8*)(lds + sb + brow + n * 2048 + kp1);
    }
    stage_half(Ag, kbN, sl1);
    stage_half(Bg, kbN, sl1 + 32768);
#pragma unroll
    for (int m = 0; m < 4; ++m)
#pragma unroll
      for (int n = 0; n < 2; ++n)
#pragma unroll
        for (int kf = 0; kf < 2; ++kf)
          acc[m][n] = __builtin_amdgcn_mfma_f32_32x32x16_bf16(a[m][kf], b[n][kf], acc[m][n], 0, 0, 0);
    asm volatile("s_waitcnt vmcnt(4)" ::: "memory");   // khi(t) arrived
    BARRIER();

    // ---- half 1 (k 32..63): read khi frags, stage khi(t+1), 16 MFMA — unpinned
#pragma unroll
    for (int m = 0; m < 4; ++m) {
      a[m][0] = *(const bf16x8*)(lds + sb + 16384 + arow + m * 2048 + kp0);
      a[m][1] = *(const bf16x8*)(lds + sb + 16384 + arow + m * 2048 + kp1);
    }
#pragma unroll
    for (int n = 0; n < 2; ++n) {
      b[n][0] = *(const bf16x8*)(lds + sb + 16384 + brow + n * 2048 + kp0);
      b[n][1] = *(const bf16x8*)(lds + sb + 16384 + brow + n * 2048 + kp1);
    }
    stage_half(Ag, kbN + 64, sl1 + 16384);
    stage_half(Bg, kbN + 64, sl1 + 49152);
#pragma unroll
    for (int m = 0; m < 4; ++m)
#pragma unroll
      for (int n = 0; n < 2; ++n)
#pragma unroll
        for (int kf = 0; kf < 2; ++kf)
          acc[m][n] = __builtin_amdgcn_mfma_f32_32x32x16_bf16(a[m][kf], b[n][kf], acc[m][n], 0, 0, 0);
    asm volatile("s_waitcnt vmcnt(4)" ::: "memory");   // klo(t+1) arrived
    BARRIER();
  }

  // ---- epilogue: C/D map col=lane&31, row=(reg&3)+8*(reg>>2)+4*(lane>>5)
#pragma unroll
  for (int mf = 0; mf < 4; ++mf) {
#pragma unroll
    for (int nf = 0; nf < 2; ++nf) {
      const int gcol = n0 + wn * 64 + nf * 32 + fr5;
      const float bv = bias[(size_t)e * N + gcol];
#pragma unroll
      for (int r = 0; r < 16; ++r) {
        const int row = (r & 3) + 8 * (r >> 2) + 4 * s5;
        const int gm = m0 + wm * 128 + mf * 32 + row;
        if (gm < cnt) {
          float v = acc[mf][nf][r] + bv;
          if (GELU) v = 0.5f * v * (1.0f + erff(v * 0.70710678118654752f));
          if (OUTBF)
            ((__hip_bfloat16*)Cout)[(size_t)(seg + gm) * N + gcol] = __float2bfloat16(v);
          else
            ((float*)Cout)[(size_t)(seg + gm) * N + gcol] = v;
        }
      }
    }
  }
}

// out[t] = g0*y[slot0] + g1*y[slot1]
__global__ void k_combine(const float* __restrict__ ybuf, const int* __restrict__ slot_of,
                          const float* __restrict__ gates, float* __restrict__ out)
{
  const int t = blockIdx.x;
  const int s0 = slot_of[2*t], s1 = slot_of[2*t+1];
  const float g0 = gates[2*t], g1 = gates[2*t+1];
  const float4 a = ((const float4*)(ybuf + (size_t)s0 * EMB))[threadIdx.x];
  const float4 b = ((const float4*)(ybuf + (size_t)s1 * EMB))[threadIdx.x];
  float4 o;
  o.x = g0 * a.x + g1 * b.x;
  o.y = g0 * a.y + g1 * b.y;
  o.z = g0 * a.z + g1 * b.z;
  o.w = g0 * a.w + g1 * b.w;
  ((float4*)(out + (size_t)t * EMB))[threadIdx.x] = o;
}

// ---------------- launch ----------------

extern "C" void kernel_launch(void* const* d_in, const int* in_sizes, int n_in,
                              void* d_out, int out_size, void* d_ws, size_t ws_size,
                              hipStream_t stream)
{
  const float* x  = (const float*)d_in[0];
  const float* Wg = (const float*)d_in[1];
  const float* bg = (const float*)d_in[2];
  const float* W1 = (const float*)d_in[3];
  const float* b1 = (const float*)d_in[4];
  const float* W2 = (const float*)d_in[5];
  const float* b2 = (const float*)d_in[6];
  const float* W3 = (const float*)d_in[7];
  const float* b3 = (const float*)d_in[8];
  float* out = (float*)d_out;

  char* ws = (char*)d_ws;
  size_t off = 0;
  auto alloc = [&](size_t bytes) -> void* {
    void* p = ws + off;
    off = (off + bytes + 255) & ~(size_t)255;
    return p;
  };

  int*   counts    = (int*)alloc(NE * 4);
  int*   fill      = (int*)alloc(NE * 4);
  int*   offsets   = (int*)alloc((NE + 1) * 4);
  int*   tmap      = (int*)alloc(MAXTILES * 4);
  int*   eidx      = (int*)alloc((size_t)TOK * 2 * 4);
  float* gates     = (float*)alloc((size_t)TOK * 2 * 4);
  int*   slot_of   = (int*)alloc((size_t)TOK * 2 * 4);
  int*   route_tok = (int*)alloc((size_t)SLOTS * 4);
  __hip_bfloat16* Wb1 = (__hip_bfloat16*)alloc((size_t)NE * EMB  * HID  * 2);
  __hip_bfloat16* Wb2 = (__hip_bfloat16*)alloc((size_t)NE * HID  * HID2 * 2);
  __hip_bfloat16* Wb3 = (__hip_bfloat16*)alloc((size_t)NE * HID2 * EMB  * 2);
  __hip_bfloat16* xg  = (__hip_bfloat16*)alloc((size_t)(SLOTS + SLACK) * EMB  * 2);
  __hip_bfloat16* h1  = (__hip_bfloat16*)alloc((size_t)(SLOTS + SLACK) * HID  * 2);
  __hip_bfloat16* h2  = (__hip_bfloat16*)alloc((size_t)(SLOTS + SLACK) * HID2 * 2);
  float*          ybuf = (float*)alloc((size_t)(SLOTS + SLACK) * EMB * 4);
  (void)ws_size; (void)in_sizes; (void)n_in; (void)out_size;

  k_init<<<1, 64, 0, stream>>>(counts, fill);
  k_gating<<<TOK / 4, 256, 0, stream>>>(x, Wg, bg, eidx, gates, counts);
  k_offsets<<<1, 1, 0, stream>>>(counts, offsets, tmap);
  k_route<<<TOK / 256, 256, 0, stream>>>(eidx, fill, offsets, route_tok, slot_of);
  k_gather<<<SLOTS, 192, 0, stream>>>(x, route_tok, xg);

  {
    dim3 b(32, 8);
    k_transpose<<<dim3(HID  / 32, EMB  / 64, NE), b, 0, stream>>>(W1, Wb1, EMB,  HID);
    k_transpose<<<dim3(HID2 / 32, HID  / 64, NE), b, 0, stream>>>(W2, Wb2, HID,  HID2);
    k_transpose<<<dim3(EMB  / 32, HID2 / 64, NE), b, 0, stream>>>(W3, Wb3, HID2, EMB);
  }

  ffn_gemm8<true,  true ><<<dim3(HID  / 256, MAXTILES), 512, 0, stream>>>(xg, Wb1, b1, h1,   counts, offsets, tmap, EMB,  HID);
  ffn_gemm8<true,  true ><<<dim3(HID2 / 256, MAXTILES), 512, 0, stream>>>(h1, Wb2, b2, h2,   counts, offsets, tmap, HID,  HID2);
  ffn_gemm8<false, false><<<dim3(EMB  / 256, MAXTILES), 512, 0, stream>>>(h2, Wb3, b3, ybuf, counts, offsets, tmap, HID2, EMB);

  k_combine<<<TOK, 192, 0, stream>>>(ybuf, slot_of, gates, out);
}

// Round 9
// 3057.286 us; speedup vs baseline: 1.0613x; 1.0613x over previous
//
#include <hip/hip_runtime.h>
#include <hip/hip_bf16.h>

#define EMB 768
#define HID 3072
#define HID2 6144
#define NE 8
#define TOK 16384    // B*N = 8*2048
#define SLOTS 32768  // TOK * top-2
#define SLACK 256    // tail-read slack rows (M-tile 256 may overrun by 255)
#define MAXTILES 136 // max active M-tiles: 128 + (NE-1) partials

typedef __attribute__((ext_vector_type(8))) short bf16x8;
typedef __attribute__((ext_vector_type(4))) float f32x4;

__device__ __forceinline__ unsigned short bfbits(float f) {
  __hip_bfloat16 h = __float2bfloat16(f);
  return __builtin_bit_cast(unsigned short, h);
}

// ---------------- init / gating / routing ----------------

__global__ void k_init(int* counts, int* fill) {
  if (threadIdx.x < NE) { counts[threadIdx.x] = 0; fill[threadIdx.x] = 0; }
}

__global__ __launch_bounds__(256) void k_gating(
    const float* __restrict__ x, const float* __restrict__ Wg,
    const float* __restrict__ bg, int* __restrict__ eidx,
    float* __restrict__ gates, int* __restrict__ counts)
{
  const int wave = threadIdx.x >> 6, lane = threadIdx.x & 63;
  const int t = blockIdx.x * 4 + wave;
  const float* xr = x + (size_t)t * EMB;
  float p[NE];
#pragma unroll
  for (int e = 0; e < NE; ++e) p[e] = 0.f;
  for (int k = lane; k < EMB; k += 64) {
    const float xv = xr[k];
    const float* wr = Wg + (size_t)k * NE;
#pragma unroll
    for (int e = 0; e < NE; ++e) p[e] += xv * wr[e];
  }
#pragma unroll
  for (int e = 0; e < NE; ++e) {
#pragma unroll
    for (int o = 32; o > 0; o >>= 1) p[e] += __shfl_xor(p[e], o);
    p[e] += bg[e];
  }
  float v0 = -1e30f, v1 = -1e30f; int i0 = 0, i1 = 0;
#pragma unroll
  for (int e = 0; e < NE; ++e) {
    const float v = p[e];
    if (v > v0)      { v1 = v0; i1 = i0; v0 = v; i0 = e; }
    else if (v > v1) { v1 = v;  i1 = e; }
  }
  const float ex = expf(v1 - v0);
  const float g0 = 1.f / (1.f + ex);
  const float g1 = 1.f - g0;
  if (lane == 0) {
    eidx[2*t] = i0; eidx[2*t+1] = i1;
    gates[2*t] = g0; gates[2*t+1] = g1;
    atomicAdd(&counts[i0], 1);
    atomicAdd(&counts[i1], 1);
  }
}

// offsets + compact (expert, m-tile) map so GEMM grid has ~no empty blocks
__global__ void k_offsets(const int* __restrict__ counts, int* __restrict__ offsets,
                          int* __restrict__ tmap)
{
  offsets[0] = 0;
  int idx = 0;
  for (int e = 0; e < NE; ++e) {
    offsets[e+1] = offsets[e] + counts[e];
    const int nt = (counts[e] + 255) >> 8;
    for (int i = 0; i < nt; ++i) tmap[idx++] = (e << 16) | i;
  }
  for (; idx < MAXTILES; ++idx) tmap[idx] = -1;
}

__global__ void k_route(const int* __restrict__ eidx, int* __restrict__ fill,
                        const int* __restrict__ offsets, int* __restrict__ route_tok,
                        int* __restrict__ slot_of, float* __restrict__ gate_slot,
                        int* __restrict__ tok_k, const float* __restrict__ gates)
{
  const int t = blockIdx.x * 256 + threadIdx.x;
  if (t >= TOK) return;
#pragma unroll
  for (int k = 0; k < 2; ++k) {
    const int e = eidx[2*t + k];
    const int pos = atomicAdd(&fill[e], 1);
    const int slot = offsets[e] + pos;
    route_tok[slot] = t;
    slot_of[2*t + k] = slot;
    gate_slot[slot] = gates[2*t + k];
    tok_k[slot] = 2*t + k;
  }
}

__global__ void k_gather(const float* __restrict__ x, const int* __restrict__ route_tok,
                         __hip_bfloat16* __restrict__ xg)
{
  const int s = blockIdx.x;
  const int t = route_tok[s];
  const float4 v = ((const float4*)(x + (size_t)t * EMB))[threadIdx.x];
  ushort4 u;
  u.x = bfbits(v.x); u.y = bfbits(v.y); u.z = bfbits(v.z); u.w = bfbits(v.w);
  *(ushort4*)((unsigned short*)xg + (size_t)s * EMB + threadIdx.x * 4) = u;
}

// unified fp32 [K,N] -> bf16 [N,K] transpose for all 3 weights, 64x64 tiles
#define NT1 (NE * (HID  / 64) * (EMB  / 64))   // 4608
#define NT2 (NE * (HID2 / 64) * (HID  / 64))   // 36864
#define NT3 (NE * (EMB  / 64) * (HID2 / 64))   // 9216

__global__ __launch_bounds__(256) void k_transpose_all(
    const float* __restrict__ W1, const float* __restrict__ W2,
    const float* __restrict__ W3, __hip_bfloat16* __restrict__ Wb1,
    __hip_bfloat16* __restrict__ Wb2, __hip_bfloat16* __restrict__ Wb3)
{
  __shared__ float tile[64][65];   // [k][n]
  int bid = blockIdx.x;
  const float* W; __hip_bfloat16* Wt; int K, N;
  if (bid < NT1)              { W = W1; Wt = Wb1; K = EMB;  N = HID;  }
  else if (bid < NT1 + NT2)   { W = W2; Wt = Wb2; K = HID;  N = HID2; bid -= NT1; }
  else                        { W = W3; Wt = Wb3; K = HID2; N = EMB;  bid -= NT1 + NT2; }
  const int ntn = N >> 6, ntk = K >> 6;
  const int e  = bid / (ntn * ntk);
  const int rem = bid - e * (ntn * ntk);
  const int k0 = (rem / ntn) << 6;
  const int n0 = (rem % ntn) << 6;

  const float* Wp = W + (size_t)e * K * N;
  __hip_bfloat16* Wtp = Wt + (size_t)e * K * N;
  const int tx = threadIdx.x, ty = threadIdx.y;

  for (int r = ty; r < 64; r += 8) {
    const float* src = Wp + (size_t)(k0 + r) * N + n0;
    tile[r][tx]      = src[tx];
    tile[r][tx + 32] = src[tx + 32];
  }
  __syncthreads();
  // write: qx = k-quad (0..15), rh splits rows; each thread 4 rows x 1 ushort4
  const int qx = tx & 15;
  const int rh = tx >> 4;
  for (int r = ty * 2 + rh; r < 64; r += 16) {
    ushort4 u;
    u.x = bfbits(tile[4 * qx + 0][r]);
    u.y = bfbits(tile[4 * qx + 1][r]);
    u.z = bfbits(tile[4 * qx + 2][r]);
    u.w = bfbits(tile[4 * qx + 3][r]);
    *(ushort4*)((unsigned short*)Wtp + (size_t)(n0 + r) * K + k0 + 4 * qx) = u;
  }
}

// ---------------- 256x256 MFMA GEMM, K-half pipeline, 2 barriers/K-tile ----
// (R6 structure verbatim: 16x16x32, conflict-free swizzle, unpinned halves.)
// SCATTER epilogue (stage-3): v = gate_slot[row] * (acc + bias); scatter to
// ybuf2[tok_k&1][token][col] — token-indexed, no atomics, deterministic.

#define BARRIER() asm volatile("s_barrier" ::: "memory")

template<bool GELU, bool OUTBF, bool SCATTER>
__global__ __launch_bounds__(512) void ffn_gemm8(
    const __hip_bfloat16* __restrict__ A,
    const __hip_bfloat16* __restrict__ Bt,
    const float* __restrict__ bias,
    void* __restrict__ Cout,
    const int* __restrict__ counts,
    const int* __restrict__ offsets,
    const int* __restrict__ tmap,
    const float* __restrict__ gate_slot,
    const int* __restrict__ tok_k,
    int K, int N)
{
  const int me = tmap[blockIdx.y];
  if (me < 0) return;
  const int e  = me >> 16;
  const int m0 = (me & 0xffff) << 8;
  const int cnt = counts[e];
  const int seg = offsets[e];
  const int n0 = blockIdx.x * 256;

  __shared__ char lds[131072];

  const int tid = threadIdx.x;
  const int wave = tid >> 6, lane = tid & 63;
  const int wm = wave >> 2, wn = wave & 3;

  const size_t KB = (size_t)K * 2;           // global row stride bytes
  const char* Ag = (const char*)(A + (size_t)(seg + m0) * K);
  const char* Bg = (const char*)(Bt + (size_t)e * N * K + (size_t)n0 * K);

  // staging: one half = 256 rows x 64B = 2 gloads x 512thr x 16B
  const int s_r  = tid >> 2;                                    // 0..127
  const int s_cb = ((tid & 3) * 16) ^ (((s_r >> 1) & 3) << 4);  // src pre-swizzle

  auto stage_half = [&](const char* gbase, int kbyte, int ldsoff) {
    const char* s = gbase + (size_t)s_r * KB + kbyte + s_cb;
    __builtin_amdgcn_global_load_lds(
        (const __attribute__((address_space(1))) void*)s,
        (__attribute__((address_space(3))) void*)(lds + ldsoff + tid * 16), 16, 0, 0);
    __builtin_amdgcn_global_load_lds(
        (const __attribute__((address_space(1))) void*)(s + 128 * KB),
        (__attribute__((address_space(3))) void*)(lds + ldsoff + 8192 + tid * 16), 16, 0, 0);
  };

  // fragment read offsets (swizzle folded: (row>>1)&3 == (fr>>1)&3)
  const int fr    = lane & 15;
  const int coff  = ((lane >> 4) * 16) ^ (((fr >> 1) & 3) << 4);
  const int aoff0 = (wm * 128 + fr) * 64 + coff;           // + frag*1024, within A-half
  const int boff0 = 32768 + (wn * 64 + fr) * 64 + coff;    // + nf*1024, within B-half

  f32x4 acc[8][4];
#pragma unroll
  for (int i = 0; i < 8; ++i)
#pragma unroll
    for (int j = 0; j < 4; ++j)
      acc[i][j] = (f32x4){0.f, 0.f, 0.f, 0.f};

  const int KT = K >> 6;

  // ---- prologue: tile0's 4 halves -> slot0, in deadline order
  stage_half(Ag, 0, 0);          // A-klo
  stage_half(Bg, 0, 32768);      // B-klo
  stage_half(Ag, 64, 16384);     // A-khi
  stage_half(Bg, 64, 49152);     // B-khi
  asm volatile("s_waitcnt vmcnt(4)" ::: "memory");   // klo pair ready
  BARRIER();

  bf16x8 a[8], b[4];

  for (int kt = 0; kt < KT; ++kt) {
    const int sb  = (kt & 1) * 65536;
    const int sl1 = sb ^ 65536;
    const int kbN = (kt + 1 < KT ? kt + 1 : KT - 1) * 128;

    // ---- half 0 (kh=0): read klo frags, stage klo(t+1), MFMA — unpinned
#pragma unroll
    for (int m = 0; m < 8; ++m)
      a[m] = *(const bf16x8*)(lds + sb + aoff0 + m * 1024);
#pragma unroll
    for (int n = 0; n < 4; ++n)
      b[n] = *(const bf16x8*)(lds + sb + boff0 + n * 1024);
    stage_half(Ag, kbN, sl1);
    stage_half(Bg, kbN, sl1 + 32768);
#pragma unroll
    for (int m = 0; m < 8; ++m)
#pragma unroll
      for (int n = 0; n < 4; ++n)
        acc[m][n] = __builtin_amdgcn_mfma_f32_16x16x32_bf16(a[m], b[n], acc[m][n], 0, 0, 0);
    asm volatile("s_waitcnt vmcnt(4)" ::: "memory");   // khi(t) arrived
    BARRIER();

    // ---- half 1 (kh=1): read khi frags, stage khi(t+1), MFMA — unpinned
#pragma unroll
    for (int m = 0; m < 8; ++m)
      a[m] = *(const bf16x8*)(lds + sb + 16384 + aoff0 + m * 1024);
#pragma unroll
    for (int n = 0; n < 4; ++n)
      b[n] = *(const bf16x8*)(lds + sb + 16384 + boff0 + n * 1024);
    stage_half(Ag, kbN + 64, sl1 + 16384);
    stage_half(Bg, kbN + 64, sl1 + 49152);
#pragma unroll
    for (int m = 0; m < 8; ++m)
#pragma unroll
      for (int n = 0; n < 4; ++n)
        acc[m][n] = __builtin_amdgcn_mfma_f32_16x16x32_bf16(a[m], b[n], acc[m][n], 0, 0, 0);
    asm volatile("s_waitcnt vmcnt(4)" ::: "memory");   // klo(t+1) arrived
    BARRIER();
  }

  // ---- epilogue: C/D map col=lane&15, row=(lane>>4)*4+r  [m89-verified]
#pragma unroll
  for (int mf = 0; mf < 8; ++mf) {
#pragma unroll
    for (int r2 = 0; r2 < 4; ++r2) {
      const int gm = m0 + wm * 128 + mf * 16 + (lane >> 4) * 4 + r2;
      if (gm >= cnt) continue;
      if (SCATTER) {
        const int s = seg + gm;
        const float g = gate_slot[s];
        const int tk = tok_k[s];
        float* dst = (float*)Cout + ((size_t)(tk & 1) * TOK + (size_t)(tk >> 1)) * EMB;
#pragma unroll
        for (int nf = 0; nf < 4; ++nf) {
          const int gcol = n0 + wn * 64 + nf * 16 + fr;
          dst[gcol] = g * (acc[mf][nf][r2] + bias[(size_t)e * N + gcol]);
        }
      } else {
#pragma unroll
        for (int nf = 0; nf < 4; ++nf) {
          const int gcol = n0 + wn * 64 + nf * 16 + fr;
          float v = acc[mf][nf][r2] + bias[(size_t)e * N + gcol];
          if (GELU) v = 0.5f * v * (1.0f + erff(v * 0.70710678118654752f));
          if (OUTBF)
            ((__hip_bfloat16*)Cout)[(size_t)(seg + gm) * N + gcol] = __float2bfloat16(v);
          else
            ((float*)Cout)[(size_t)(seg + gm) * N + gcol] = v;
        }
      }
    }
  }
}

// out = y0 + y1 (token-indexed, fully coalesced)
__global__ __launch_bounds__(256) void k_combine2(const float* __restrict__ ybuf2,
                                                  float* __restrict__ out)
{
  const size_t total = (size_t)TOK * EMB / 4;
  for (size_t i = blockIdx.x * 256 + threadIdx.x; i < total; i += (size_t)gridDim.x * 256) {
    const float4 a = ((const float4*)ybuf2)[i];
    const float4 b = ((const float4*)(ybuf2 + (size_t)TOK * EMB))[i];
    float4 o;
    o.x = a.x + b.x; o.y = a.y + b.y; o.z = a.z + b.z; o.w = a.w + b.w;
    ((float4*)out)[i] = o;
  }
}

// ---------------- launch ----------------

extern "C" void kernel_launch(void* const* d_in, const int* in_sizes, int n_in,
                              void* d_out, int out_size, void* d_ws, size_t ws_size,
                              hipStream_t stream)
{
  const float* x  = (const float*)d_in[0];
  const float* Wg = (const float*)d_in[1];
  const float* bg = (const float*)d_in[2];
  const float* W1 = (const float*)d_in[3];
  const float* b1 = (const float*)d_in[4];
  const float* W2 = (const float*)d_in[5];
  const float* b2 = (const float*)d_in[6];
  const float* W3 = (const float*)d_in[7];
  const float* b3 = (const float*)d_in[8];
  float* out = (float*)d_out;

  char* ws = (char*)d_ws;
  size_t off = 0;
  auto alloc = [&](size_t bytes) -> void* {
    void* p = ws + off;
    off = (off + bytes + 255) & ~(size_t)255;
    return p;
  };

  int*   counts    = (int*)alloc(NE * 4);
  int*   fill      = (int*)alloc(NE * 4);
  int*   offsets   = (int*)alloc((NE + 1) * 4);
  int*   tmap      = (int*)alloc(MAXTILES * 4);
  int*   eidx      = (int*)alloc((size_t)TOK * 2 * 4);
  float* gates     = (float*)alloc((size_t)TOK * 2 * 4);
  int*   slot_of   = (int*)alloc((size_t)TOK * 2 * 4);
  int*   route_tok = (int*)alloc((size_t)SLOTS * 4);
  float* gate_slot = (float*)alloc((size_t)(SLOTS + SLACK) * 4);
  int*   tok_k     = (int*)alloc((size_t)(SLOTS + SLACK) * 4);
  __hip_bfloat16* Wb1 = (__hip_bfloat16*)alloc((size_t)NE * EMB  * HID  * 2);
  __hip_bfloat16* Wb2 = (__hip_bfloat16*)alloc((size_t)NE * HID  * HID2 * 2);
  __hip_bfloat16* Wb3 = (__hip_bfloat16*)alloc((size_t)NE * HID2 * EMB  * 2);
  __hip_bfloat16* xg  = (__hip_bfloat16*)alloc((size_t)(SLOTS + SLACK) * EMB  * 2);
  __hip_bfloat16* h1  = (__hip_bfloat16*)alloc((size_t)(SLOTS + SLACK) * HID  * 2);
  __hip_bfloat16* h2  = (__hip_bfloat16*)alloc((size_t)(SLOTS + SLACK) * HID2 * 2);
  float*          ybuf2 = (float*)alloc((size_t)2 * TOK * EMB * 4);
  (void)ws_size; (void)in_sizes; (void)n_in; (void)out_size;

  k_init<<<1, 64, 0, stream>>>(counts, fill);
  k_gating<<<TOK / 4, 256, 0, stream>>>(x, Wg, bg, eidx, gates, counts);
  k_offsets<<<1, 1, 0, stream>>>(counts, offsets, tmap);
  k_route<<<TOK / 256, 256, 0, stream>>>(eidx, fill, offsets, route_tok, slot_of,
                                         gate_slot, tok_k, gates);
  k_gather<<<SLOTS, 192, 0, stream>>>(x, route_tok, xg);

  k_transpose_all<<<NT1 + NT2 + NT3, dim3(32, 8), 0, stream>>>(W1, W2, W3, Wb1, Wb2, Wb3);

  ffn_gemm8<true,  true,  false><<<dim3(HID  / 256, MAXTILES), 512, 0, stream>>>(
      xg, Wb1, b1, h1, counts, offsets, tmap, nullptr, nullptr, EMB,  HID);
  ffn_gemm8<true,  true,  false><<<dim3(HID2 / 256, MAXTILES), 512, 0, stream>>>(
      h1, Wb2, b2, h2, counts, offsets, tmap, nullptr, nullptr, HID,  HID2);
  ffn_gemm8<false, false, true ><<<dim3(EMB  / 256, MAXTILES), 512, 0, stream>>>(
      h2, Wb3, b3, ybuf2, counts, offsets, tmap, gate_slot, tok_k, HID2, EMB);

  k_combine2<<<2048, 256, 0, stream>>>(ybuf2, out);
}

// Round 10
// 2572.000 us; speedup vs baseline: 1.2615x; 1.1887x over previous
//
#include <hip/hip_runtime.h>
#include <hip/hip_bf16.h>

#define EMB 768
#define HID 3072
#define HID2 6144
#define NE 8
#define TOK 16384    // B*N = 8*2048
#define SLOTS 32768  // TOK * top-2
#define SLACK 256    // tail-read slack rows (M-tile 256 may overrun by 255)
#define MAXTILES 136 // max active M-tiles: 128 + (NE-1) partials

typedef __attribute__((ext_vector_type(8))) short bf16x8;
typedef __attribute__((ext_vector_type(4))) float f32x4;

__device__ __forceinline__ unsigned short bfbits(float f) {
  __hip_bfloat16 h = __float2bfloat16(f);
  return __builtin_bit_cast(unsigned short, h);
}

// ---------------- init / gating / routing ----------------

__global__ void k_init(int* counts, int* fill) {
  if (threadIdx.x < NE) { counts[threadIdx.x] = 0; fill[threadIdx.x] = 0; }
}

// gating: scores, top-2, softmax — NO atomics (counts done by k_count)
__global__ __launch_bounds__(256) void k_gating(
    const float* __restrict__ x, const float* __restrict__ Wg,
    const float* __restrict__ bg, int* __restrict__ eidx,
    float* __restrict__ gates)
{
  const int wave = threadIdx.x >> 6, lane = threadIdx.x & 63;
  const int t = blockIdx.x * 4 + wave;
  const float* xr = x + (size_t)t * EMB;
  float p[NE];
#pragma unroll
  for (int e = 0; e < NE; ++e) p[e] = 0.f;
  for (int k = lane; k < EMB; k += 64) {
    const float xv = xr[k];
    const float* wr = Wg + (size_t)k * NE;
#pragma unroll
    for (int e = 0; e < NE; ++e) p[e] += xv * wr[e];
  }
#pragma unroll
  for (int e = 0; e < NE; ++e) {
#pragma unroll
    for (int o = 32; o > 0; o >>= 1) p[e] += __shfl_xor(p[e], o);
    p[e] += bg[e];
  }
  float v0 = -1e30f, v1 = -1e30f; int i0 = 0, i1 = 0;
#pragma unroll
  for (int e = 0; e < NE; ++e) {
    const float v = p[e];
    if (v > v0)      { v1 = v0; i1 = i0; v0 = v; i0 = e; }
    else if (v > v1) { v1 = v;  i1 = e; }
  }
  const float ex = expf(v1 - v0);
  const float g0 = 1.f / (1.f + ex);
  const float g1 = 1.f - g0;
  if (lane == 0) {
    eidx[2*t] = i0; eidx[2*t+1] = i1;
    gates[2*t] = g0; gates[2*t+1] = g1;
  }
}

// block-aggregated expert histogram: 512 entries/block, 8 global atomics/block
__global__ __launch_bounds__(256) void k_count(const int* __restrict__ eidx,
                                               int* __restrict__ counts)
{
  __shared__ int bins[NE];
  if (threadIdx.x < NE) bins[threadIdx.x] = 0;
  __syncthreads();
  const int base = blockIdx.x * 512 + threadIdx.x * 2;
  atomicAdd(&bins[eidx[base]], 1);
  atomicAdd(&bins[eidx[base + 1]], 1);
  __syncthreads();
  if (threadIdx.x < NE) atomicAdd(&counts[threadIdx.x], bins[threadIdx.x]);
}

// offsets + compact (expert, m-tile) map so GEMM grid has ~no empty blocks
__global__ void k_offsets(const int* __restrict__ counts, int* __restrict__ offsets,
                          int* __restrict__ tmap)
{
  offsets[0] = 0;
  int idx = 0;
  for (int e = 0; e < NE; ++e) {
    offsets[e+1] = offsets[e] + counts[e];
    const int nt = (counts[e] + 255) >> 8;
    for (int i = 0; i < nt; ++i) tmap[idx++] = (e << 16) | i;
  }
  for (; idx < MAXTILES; ++idx) tmap[idx] = -1;
}

// block-aggregated routing: LDS local positions + 8 global atomics/block
__global__ __launch_bounds__(256) void k_route(
    const int* __restrict__ eidx, int* __restrict__ fill,
    const int* __restrict__ offsets, int* __restrict__ route_tok,
    float* __restrict__ gate_slot, int* __restrict__ tok_k,
    const float* __restrict__ gates)
{
  __shared__ int bins[NE], base[NE];
  const int tid = threadIdx.x;
  if (tid < NE) bins[tid] = 0;
  __syncthreads();
  const int t = blockIdx.x * 256 + tid;
  int e0 = eidx[2*t], e1 = eidx[2*t+1];
  int lp0 = atomicAdd(&bins[e0], 1);
  int lp1 = atomicAdd(&bins[e1], 1);
  __syncthreads();
  if (tid < NE) base[tid] = atomicAdd(&fill[tid], bins[tid]);
  __syncthreads();
  const int s0 = offsets[e0] + base[e0] + lp0;
  const int s1 = offsets[e1] + base[e1] + lp1;
  route_tok[s0] = t;          route_tok[s1] = t;
  gate_slot[s0] = gates[2*t]; gate_slot[s1] = gates[2*t+1];
  tok_k[s0] = 2*t;            tok_k[s1] = 2*t + 1;
}

// gather x rows -> compacted bf16 A; wave per slot, 4 slots/block
__global__ __launch_bounds__(256) void k_gather(
    const float* __restrict__ x, const int* __restrict__ route_tok,
    __hip_bfloat16* __restrict__ xg)
{
  const int w = threadIdx.x >> 6, lane = threadIdx.x & 63;
  const int s = blockIdx.x * 4 + w;
  const int t = route_tok[s];
  const float4* src = (const float4*)(x + (size_t)t * EMB);
  unsigned short* dst = (unsigned short*)xg + (size_t)s * EMB;
#pragma unroll
  for (int i = 0; i < 3; ++i) {
    const float4 v = src[lane + 64 * i];
    ushort4 u;
    u.x = bfbits(v.x); u.y = bfbits(v.y); u.z = bfbits(v.z); u.w = bfbits(v.w);
    *(ushort4*)(dst + (lane + 64 * i) * 4) = u;
  }
}

// unified fp32 [K,N] -> bf16 [N,K] transpose, 64x64 tiles,
// float4 global reads + ushort8 (16B) global writes; [65] pad = <=2-way LDS
#define NT1 (NE * (HID  / 64) * (EMB  / 64))   // 4608
#define NT2 (NE * (HID2 / 64) * (HID  / 64))   // 36864
#define NT3 (NE * (EMB  / 64) * (HID2 / 64))   // 9216

typedef __attribute__((ext_vector_type(8))) unsigned short u16x8;

__global__ __launch_bounds__(256) void k_transpose_all(
    const float* __restrict__ W1, const float* __restrict__ W2,
    const float* __restrict__ W3, __hip_bfloat16* __restrict__ Wb1,
    __hip_bfloat16* __restrict__ Wb2, __hip_bfloat16* __restrict__ Wb3)
{
  __shared__ float tile[64][65];   // [k][n]
  int bid = blockIdx.x;
  const float* W; __hip_bfloat16* Wt; int K, N;
  if (bid < NT1)              { W = W1; Wt = Wb1; K = EMB;  N = HID;  }
  else if (bid < NT1 + NT2)   { W = W2; Wt = Wb2; K = HID;  N = HID2; bid -= NT1; }
  else                        { W = W3; Wt = Wb3; K = HID2; N = EMB;  bid -= NT1 + NT2; }
  const int ntn = N >> 6, ntk = K >> 6;
  const int e  = bid / (ntn * ntk);
  const int rem = bid - e * (ntn * ntk);
  const int k0 = (rem / ntn) << 6;
  const int n0 = (rem % ntn) << 6;

  const float* Wp = W + (size_t)e * K * N;
  __hip_bfloat16* Wtp = Wt + (size_t)e * K * N;
  const int tx = threadIdx.x, ty = threadIdx.y;   // 32 x 8

  // read: 16 rows/iter, thread covers one float4 (q = tx&15, rsub = tx>>4)
  const int q = tx & 15, rsub = tx >> 4;
#pragma unroll
  for (int it = 0; it < 4; ++it) {
    const int r = it * 16 + ty * 2 + rsub;
    const float4 v = *(const float4*)(Wp + (size_t)(k0 + r) * N + n0 + 4 * q);
    tile[r][4 * q]     = v.x;
    tile[r][4 * q + 1] = v.y;
    tile[r][4 * q + 2] = v.z;
    tile[r][4 * q + 3] = v.w;
  }
  __syncthreads();
  // write: 32 n-rows/iter; thread covers 8 k's (q8 = tx&7) as one ushort8
  const int q8 = tx & 7, r8 = tx >> 3;
#pragma unroll
  for (int it = 0; it < 2; ++it) {
    const int n = it * 32 + ty * 4 + r8;
    u16x8 u;
#pragma unroll
    for (int j = 0; j < 8; ++j) u[j] = bfbits(tile[8 * q8 + j][n]);
    *(u16x8*)((unsigned short*)Wtp + (size_t)(n0 + n) * K + k0 + 8 * q8) = u;
  }
}

// ---------------- 256x256 MFMA GEMM, K-half pipeline, 2 barriers/K-tile ----
// (R6/R9 structure verbatim: 16x16x32, conflict-free swizzle, unpinned halves.)
// SCATTER epilogue (stage-3): v = gate_slot[row] * (acc + bias); scatter to
// ybuf2[tok_k&1][token][col] — token-indexed, no atomics, deterministic.

#define BARRIER() asm volatile("s_barrier" ::: "memory")

template<bool GELU, bool OUTBF, bool SCATTER>
__global__ __launch_bounds__(512) void ffn_gemm8(
    const __hip_bfloat16* __restrict__ A,
    const __hip_bfloat16* __restrict__ Bt,
    const float* __restrict__ bias,
    void* __restrict__ Cout,
    const int* __restrict__ counts,
    const int* __restrict__ offsets,
    const int* __restrict__ tmap,
    const float* __restrict__ gate_slot,
    const int* __restrict__ tok_k,
    int K, int N)
{
  const int me = tmap[blockIdx.y];
  if (me < 0) return;
  const int e  = me >> 16;
  const int m0 = (me & 0xffff) << 8;
  const int cnt = counts[e];
  const int seg = offsets[e];
  const int n0 = blockIdx.x * 256;

  __shared__ char lds[131072];

  const int tid = threadIdx.x;
  const int wave = tid >> 6, lane = tid & 63;
  const int wm = wave >> 2, wn = wave & 3;

  const size_t KB = (size_t)K * 2;           // global row stride bytes
  const char* Ag = (const char*)(A + (size_t)(seg + m0) * K);
  const char* Bg = (const char*)(Bt + (size_t)e * N * K + (size_t)n0 * K);

  // staging: one half = 256 rows x 64B = 2 gloads x 512thr x 16B
  const int s_r  = tid >> 2;                                    // 0..127
  const int s_cb = ((tid & 3) * 16) ^ (((s_r >> 1) & 3) << 4);  // src pre-swizzle

  auto stage_half = [&](const char* gbase, int kbyte, int ldsoff) {
    const char* s = gbase + (size_t)s_r * KB + kbyte + s_cb;
    __builtin_amdgcn_global_load_lds(
        (const __attribute__((address_space(1))) void*)s,
        (__attribute__((address_space(3))) void*)(lds + ldsoff + tid * 16), 16, 0, 0);
    __builtin_amdgcn_global_load_lds(
        (const __attribute__((address_space(1))) void*)(s + 128 * KB),
        (__attribute__((address_space(3))) void*)(lds + ldsoff + 8192 + tid * 16), 16, 0, 0);
  };

  // fragment read offsets (swizzle folded: (row>>1)&3 == (fr>>1)&3)
  const int fr    = lane & 15;
  const int coff  = ((lane >> 4) * 16) ^ (((fr >> 1) & 3) << 4);
  const int aoff0 = (wm * 128 + fr) * 64 + coff;           // + frag*1024, within A-half
  const int boff0 = 32768 + (wn * 64 + fr) * 64 + coff;    // + nf*1024, within B-half

  f32x4 acc[8][4];
#pragma unroll
  for (int i = 0; i < 8; ++i)
#pragma unroll
    for (int j = 0; j < 4; ++j)
      acc[i][j] = (f32x4){0.f, 0.f, 0.f, 0.f};

  const int KT = K >> 6;

  // ---- prologue: tile0's 4 halves -> slot0, in deadline order
  stage_half(Ag, 0, 0);          // A-klo
  stage_half(Bg, 0, 32768);      // B-klo
  stage_half(Ag, 64, 16384);     // A-khi
  stage_half(Bg, 64, 49152);     // B-khi
  asm volatile("s_waitcnt vmcnt(4)" ::: "memory");   // klo pair ready
  BARRIER();

  bf16x8 a[8], b[4];

  for (int kt = 0; kt < KT; ++kt) {
    const int sb  = (kt & 1) * 65536;
    const int sl1 = sb ^ 65536;
    const int kbN = (kt + 1 < KT ? kt + 1 : KT - 1) * 128;

    // ---- half 0 (kh=0): read klo frags, stage klo(t+1), MFMA — unpinned
#pragma unroll
    for (int m = 0; m < 8; ++m)
      a[m] = *(const bf16x8*)(lds + sb + aoff0 + m * 1024);
#pragma unroll
    for (int n = 0; n < 4; ++n)
      b[n] = *(const bf16x8*)(lds + sb + boff0 + n * 1024);
    stage_half(Ag, kbN, sl1);
    stage_half(Bg, kbN, sl1 + 32768);
#pragma unroll
    for (int m = 0; m < 8; ++m)
#pragma unroll
      for (int n = 0; n < 4; ++n)
        acc[m][n] = __builtin_amdgcn_mfma_f32_16x16x32_bf16(a[m], b[n], acc[m][n], 0, 0, 0);
    asm volatile("s_waitcnt vmcnt(4)" ::: "memory");   // khi(t) arrived
    BARRIER();

    // ---- half 1 (kh=1): read khi frags, stage khi(t+1), MFMA — unpinned
#pragma unroll
    for (int m = 0; m < 8; ++m)
      a[m] = *(const bf16x8*)(lds + sb + 16384 + aoff0 + m * 1024);
#pragma unroll
    for (int n = 0; n < 4; ++n)
      b[n] = *(const bf16x8*)(lds + sb + 16384 + boff0 + n * 1024);
    stage_half(Ag, kbN + 64, sl1 + 16384);
    stage_half(Bg, kbN + 64, sl1 + 49152);
#pragma unroll
    for (int m = 0; m < 8; ++m)
#pragma unroll
      for (int n = 0; n < 4; ++n)
        acc[m][n] = __builtin_amdgcn_mfma_f32_16x16x32_bf16(a[m], b[n], acc[m][n], 0, 0, 0);
    asm volatile("s_waitcnt vmcnt(4)" ::: "memory");   // klo(t+1) arrived
    BARRIER();
  }

  // ---- epilogue: C/D map col=lane&15, row=(lane>>4)*4+r  [m89-verified]
#pragma unroll
  for (int mf = 0; mf < 8; ++mf) {
#pragma unroll
    for (int r2 = 0; r2 < 4; ++r2) {
      const int gm = m0 + wm * 128 + mf * 16 + (lane >> 4) * 4 + r2;
      if (gm >= cnt) continue;
      if (SCATTER) {
        const int s = seg + gm;
        const float g = gate_slot[s];
        const int tk = tok_k[s];
        float* dst = (float*)Cout + ((size_t)(tk & 1) * TOK + (size_t)(tk >> 1)) * EMB;
#pragma unroll
        for (int nf = 0; nf < 4; ++nf) {
          const int gcol = n0 + wn * 64 + nf * 16 + fr;
          dst[gcol] = g * (acc[mf][nf][r2] + bias[(size_t)e * N + gcol]);
        }
      } else {
#pragma unroll
        for (int nf = 0; nf < 4; ++nf) {
          const int gcol = n0 + wn * 64 + nf * 16 + fr;
          float v = acc[mf][nf][r2] + bias[(size_t)e * N + gcol];
          if (GELU) v = 0.5f * v * (1.0f + erff(v * 0.70710678118654752f));
          if (OUTBF)
            ((__hip_bfloat16*)Cout)[(size_t)(seg + gm) * N + gcol] = __float2bfloat16(v);
          else
            ((float*)Cout)[(size_t)(seg + gm) * N + gcol] = v;
        }
      }
    }
  }
}

// out = y0 + y1 (token-indexed, fully coalesced)
__global__ __launch_bounds__(256) void k_combine2(const float* __restrict__ ybuf2,
                                                  float* __restrict__ out)
{
  const size_t total = (size_t)TOK * EMB / 4;
  for (size_t i = blockIdx.x * 256 + threadIdx.x; i < total; i += (size_t)gridDim.x * 256) {
    const float4 a = ((const float4*)ybuf2)[i];
    const float4 b = ((const float4*)(ybuf2 + (size_t)TOK * EMB))[i];
    float4 o;
    o.x = a.x + b.x; o.y = a.y + b.y; o.z = a.z + b.z; o.w = a.w + b.w;
    ((float4*)out)[i] = o;
  }
}

// ---------------- launch ----------------

extern "C" void kernel_launch(void* const* d_in, const int* in_sizes, int n_in,
                              void* d_out, int out_size, void* d_ws, size_t ws_size,
                              hipStream_t stream)
{
  const float* x  = (const float*)d_in[0];
  const float* Wg = (const float*)d_in[1];
  const float* bg = (const float*)d_in[2];
  const float* W1 = (const float*)d_in[3];
  const float* b1 = (const float*)d_in[4];
  const float* W2 = (const float*)d_in[5];
  const float* b2 = (const float*)d_in[6];
  const float* W3 = (const float*)d_in[7];
  const float* b3 = (const float*)d_in[8];
  float* out = (float*)d_out;

  char* ws = (char*)d_ws;
  size_t off = 0;
  auto alloc = [&](size_t bytes) -> void* {
    void* p = ws + off;
    off = (off + bytes + 255) & ~(size_t)255;
    return p;
  };

  int*   counts    = (int*)alloc(NE * 4);
  int*   fill      = (int*)alloc(NE * 4);
  int*   offsets   = (int*)alloc((NE + 1) * 4);
  int*   tmap      = (int*)alloc(MAXTILES * 4);
  int*   eidx      = (int*)alloc((size_t)TOK * 2 * 4);
  float* gates     = (float*)alloc((size_t)TOK * 2 * 4);
  int*   route_tok = (int*)alloc((size_t)SLOTS * 4);
  float* gate_slot = (float*)alloc((size_t)(SLOTS + SLACK) * 4);
  int*   tok_k     = (int*)alloc((size_t)(SLOTS + SLACK) * 4);
  __hip_bfloat16* Wb1 = (__hip_bfloat16*)alloc((size_t)NE * EMB  * HID  * 2);
  __hip_bfloat16* Wb2 = (__hip_bfloat16*)alloc((size_t)NE * HID  * HID2 * 2);
  __hip_bfloat16* Wb3 = (__hip_bfloat16*)alloc((size_t)NE * HID2 * EMB  * 2);
  __hip_bfloat16* xg  = (__hip_bfloat16*)alloc((size_t)(SLOTS + SLACK) * EMB  * 2);
  __hip_bfloat16* h1  = (__hip_bfloat16*)alloc((size_t)(SLOTS + SLACK) * HID  * 2);
  __hip_bfloat16* h2  = (__hip_bfloat16*)alloc((size_t)(SLOTS + SLACK) * HID2 * 2);
  float*          ybuf2 = (float*)alloc((size_t)2 * TOK * EMB * 4);
  (void)ws_size; (void)in_sizes; (void)n_in; (void)out_size;

  k_init<<<1, 64, 0, stream>>>(counts, fill);
  k_gating<<<TOK / 4, 256, 0, stream>>>(x, Wg, bg, eidx, gates);
  k_count<<<SLOTS / 512, 256, 0, stream>>>(eidx, counts);
  k_offsets<<<1, 1, 0, stream>>>(counts, offsets, tmap);
  k_route<<<TOK / 256, 256, 0, stream>>>(eidx, fill, offsets, route_tok,
                                         gate_slot, tok_k, gates);
  k_gather<<<SLOTS / 4, 256, 0, stream>>>(x, route_tok, xg);

  k_transpose_all<<<NT1 + NT2 + NT3, dim3(32, 8), 0, stream>>>(W1, W2, W3, Wb1, Wb2, Wb3);

  ffn_gemm8<true,  true,  false><<<dim3(HID  / 256, MAXTILES), 512, 0, stream>>>(
      xg, Wb1, b1, h1, counts, offsets, tmap, nullptr, nullptr, EMB,  HID);
  ffn_gemm8<true,  true,  false><<<dim3(HID2 / 256, MAXTILES), 512, 0, stream>>>(
      h1, Wb2, b2, h2, counts, offsets, tmap, nullptr, nullptr, HID,  HID2);
  ffn_gemm8<false, false, true ><<<dim3(EMB  / 256, MAXTILES), 512, 0, stream>>>(
      h2, Wb3, b3, ybuf2, counts, offsets, tmap, gate_slot, tok_k, HID2, EMB);

  k_combine2<<<2048, 256, 0, stream>>>(ybuf2, out);
}

// Round 11
// 2434.492 us; speedup vs baseline: 1.3328x; 1.0565x over previous
//
#include <hip/hip_runtime.h>
#include <hip/hip_bf16.h>

#define EMB 768
#define HID 3072
#define HID2 6144
#define NE 8
#define TOK 16384    // B*N = 8*2048
#define SLOTS 32768  // TOK * top-2
#define SLACK 256    // tail-read slack rows (M-tile 256 may overrun by 255)
#define MAXTILES 136 // max active M-tiles: 128 + (NE-1) partials

typedef __attribute__((ext_vector_type(8))) short bf16x8;
typedef __attribute__((ext_vector_type(4))) float f32x4;

__device__ __forceinline__ unsigned short bfbits(float f) {
  __hip_bfloat16 h = __float2bfloat16(f);
  return __builtin_bit_cast(unsigned short, h);
}

// ---------------- init / gating / routing ----------------

__global__ void k_init(int* counts, int* fill) {
  if (threadIdx.x < NE) { counts[threadIdx.x] = 0; fill[threadIdx.x] = 0; }
}

__global__ __launch_bounds__(256) void k_gating(
    const float* __restrict__ x, const float* __restrict__ Wg,
    const float* __restrict__ bg, int* __restrict__ eidx,
    float* __restrict__ gates)
{
  const int wave = threadIdx.x >> 6, lane = threadIdx.x & 63;
  const int t = blockIdx.x * 4 + wave;
  const float* xr = x + (size_t)t * EMB;
  float p[NE];
#pragma unroll
  for (int e = 0; e < NE; ++e) p[e] = 0.f;
  for (int k = lane; k < EMB; k += 64) {
    const float xv = xr[k];
    const float* wr = Wg + (size_t)k * NE;
#pragma unroll
    for (int e = 0; e < NE; ++e) p[e] += xv * wr[e];
  }
#pragma unroll
  for (int e = 0; e < NE; ++e) {
#pragma unroll
    for (int o = 32; o > 0; o >>= 1) p[e] += __shfl_xor(p[e], o);
    p[e] += bg[e];
  }
  float v0 = -1e30f, v1 = -1e30f; int i0 = 0, i1 = 0;
#pragma unroll
  for (int e = 0; e < NE; ++e) {
    const float v = p[e];
    if (v > v0)      { v1 = v0; i1 = i0; v0 = v; i0 = e; }
    else if (v > v1) { v1 = v;  i1 = e; }
  }
  const float ex = expf(v1 - v0);
  const float g0 = 1.f / (1.f + ex);
  const float g1 = 1.f - g0;
  if (lane == 0) {
    eidx[2*t] = i0; eidx[2*t+1] = i1;
    gates[2*t] = g0; gates[2*t+1] = g1;
  }
}

__global__ __launch_bounds__(256) void k_count(const int* __restrict__ eidx,
                                               int* __restrict__ counts)
{
  __shared__ int bins[NE];
  if (threadIdx.x < NE) bins[threadIdx.x] = 0;
  __syncthreads();
  const int base = blockIdx.x * 512 + threadIdx.x * 2;
  atomicAdd(&bins[eidx[base]], 1);
  atomicAdd(&bins[eidx[base + 1]], 1);
  __syncthreads();
  if (threadIdx.x < NE) atomicAdd(&counts[threadIdx.x], bins[threadIdx.x]);
}

__global__ void k_offsets(const int* __restrict__ counts, int* __restrict__ offsets,
                          int* __restrict__ tmap)
{
  offsets[0] = 0;
  int idx = 0;
  for (int e = 0; e < NE; ++e) {
    offsets[e+1] = offsets[e] + counts[e];
    const int nt = (counts[e] + 255) >> 8;
    for (int i = 0; i < nt; ++i) tmap[idx++] = (e << 16) | i;
  }
  for (; idx < MAXTILES; ++idx) tmap[idx] = -1;
}

__global__ __launch_bounds__(256) void k_route(
    const int* __restrict__ eidx, int* __restrict__ fill,
    const int* __restrict__ offsets, int* __restrict__ route_tok,
    float* __restrict__ gate_slot, int* __restrict__ tok_k,
    const float* __restrict__ gates)
{
  __shared__ int bins[NE], base[NE];
  const int tid = threadIdx.x;
  if (tid < NE) bins[tid] = 0;
  __syncthreads();
  const int t = blockIdx.x * 256 + tid;
  int e0 = eidx[2*t], e1 = eidx[2*t+1];
  int lp0 = atomicAdd(&bins[e0], 1);
  int lp1 = atomicAdd(&bins[e1], 1);
  __syncthreads();
  if (tid < NE) base[tid] = atomicAdd(&fill[tid], bins[tid]);
  __syncthreads();
  const int s0 = offsets[e0] + base[e0] + lp0;
  const int s1 = offsets[e1] + base[e1] + lp1;
  route_tok[s0] = t;          route_tok[s1] = t;
  gate_slot[s0] = gates[2*t]; gate_slot[s1] = gates[2*t+1];
  tok_k[s0] = 2*t;            tok_k[s1] = 2*t + 1;
}

__global__ __launch_bounds__(256) void k_gather(
    const float* __restrict__ x, const int* __restrict__ route_tok,
    __hip_bfloat16* __restrict__ xg)
{
  const int w = threadIdx.x >> 6, lane = threadIdx.x & 63;
  const int s = blockIdx.x * 4 + w;
  const int t = route_tok[s];
  const float4* src = (const float4*)(x + (size_t)t * EMB);
  unsigned short* dst = (unsigned short*)xg + (size_t)s * EMB;
#pragma unroll
  for (int i = 0; i < 3; ++i) {
    const float4 v = src[lane + 64 * i];
    ushort4 u;
    u.x = bfbits(v.x); u.y = bfbits(v.y); u.z = bfbits(v.z); u.w = bfbits(v.w);
    *(ushort4*)(dst + (lane + 64 * i) * 4) = u;
  }
}

// unified fp32 [K,N] -> bf16 [N,K] transpose, 64x64 tiles
#define NT1 (NE * (HID  / 64) * (EMB  / 64))   // 4608
#define NT2 (NE * (HID2 / 64) * (HID  / 64))   // 36864
#define NT3 (NE * (EMB  / 64) * (HID2 / 64))   // 9216

typedef __attribute__((ext_vector_type(8))) unsigned short u16x8;

__global__ __launch_bounds__(256) void k_transpose_all(
    const float* __restrict__ W1, const float* __restrict__ W2,
    const float* __restrict__ W3, __hip_bfloat16* __restrict__ Wb1,
    __hip_bfloat16* __restrict__ Wb2, __hip_bfloat16* __restrict__ Wb3)
{
  __shared__ float tile[64][65];   // [k][n]
  int bid = blockIdx.x;
  const float* W; __hip_bfloat16* Wt; int K, N;
  if (bid < NT1)              { W = W1; Wt = Wb1; K = EMB;  N = HID;  }
  else if (bid < NT1 + NT2)   { W = W2; Wt = Wb2; K = HID;  N = HID2; bid -= NT1; }
  else                        { W = W3; Wt = Wb3; K = HID2; N = EMB;  bid -= NT1 + NT2; }
  const int ntn = N >> 6, ntk = K >> 6;
  const int e  = bid / (ntn * ntk);
  const int rem = bid - e * (ntn * ntk);
  const int k0 = (rem / ntn) << 6;
  const int n0 = (rem % ntn) << 6;

  const float* Wp = W + (size_t)e * K * N;
  __hip_bfloat16* Wtp = Wt + (size_t)e * K * N;
  const int tx = threadIdx.x, ty = threadIdx.y;   // 32 x 8

  const int q = tx & 15, rsub = tx >> 4;
#pragma unroll
  for (int it = 0; it < 4; ++it) {
    const int r = it * 16 + ty * 2 + rsub;
    const float4 v = *(const float4*)(Wp + (size_t)(k0 + r) * N + n0 + 4 * q);
    tile[r][4 * q]     = v.x;
    tile[r][4 * q + 1] = v.y;
    tile[r][4 * q + 2] = v.z;
    tile[r][4 * q + 3] = v.w;
  }
  __syncthreads();
  const int q8 = tx & 7, r8 = tx >> 3;
#pragma unroll
  for (int it = 0; it < 2; ++it) {
    const int n = it * 32 + ty * 4 + r8;
    u16x8 u;
#pragma unroll
    for (int j = 0; j < 8; ++j) u[j] = bfbits(tile[8 * q8 + j][n]);
    *(u16x8*)((unsigned short*)Wtp + (size_t)(n0 + n) * K + k0 + 8 * q8) = u;
  }
}

// ---- 256x256 MFMA GEMM, 4-half-unit rotation, cross-phase read-ahead ------
// A: bf16 [slots, K] (per-expert segments); Bt: bf16 [NE, N, K].
// BM=BN=256, 8 waves (2M x 4N), per-wave 128x64 C. Half = 32 k's.
// LDS = 4 units x 32KB (A-half 16KB | B-half 16KB); unit u holds half H_x, x%4==u.
// Phase p: issue 12 ds_reads R(H_p) [H_p published at bar(p-1)]; stage S(H_{p+2});
// lgkmcnt(12) [drains R(H_{p-1}), leaves R(H_p) in flight]; sched_barrier;
// 32 MFMA on H_{p-1} — overlaps R(H_p)'s LDS service; vmcnt(4) [drains S(H_{p+1}),
// keeps S(H_{p+2}) in flight]; s_barrier [publishes H_{p+1}].
// Swizzle (R4/R6-verified conflict-free for 64B rows): slot ^= ((row>>1)&3)<<4
// on global SOURCE (linear gload_lds dest) + ds_read addr.
// Frag regs double-buffered with NAMED sets (E/O) — no runtime indexing.

#define BARRIER() asm volatile("s_barrier" ::: "memory")
#define LGKM(n) { asm volatile("s_waitcnt lgkmcnt(" #n ")" ::: "memory"); __builtin_amdgcn_sched_barrier(0); }
#define VMC(n)  { asm volatile("s_waitcnt vmcnt(" #n ")" ::: "memory"); __builtin_amdgcn_sched_barrier(0); }

template<bool GELU, bool OUTBF, bool SCATTER>
__global__ __launch_bounds__(512) void ffn_gemm8(
    const __hip_bfloat16* __restrict__ A,
    const __hip_bfloat16* __restrict__ Bt,
    const float* __restrict__ bias,
    void* __restrict__ Cout,
    const int* __restrict__ counts,
    const int* __restrict__ offsets,
    const int* __restrict__ tmap,
    const float* __restrict__ gate_slot,
    const int* __restrict__ tok_k,
    int K, int N)
{
  const int me = tmap[blockIdx.y];
  if (me < 0) return;
  const int e  = me >> 16;
  const int m0 = (me & 0xffff) << 8;
  const int cnt = counts[e];
  const int seg = offsets[e];
  const int n0 = blockIdx.x * 256;

  __shared__ char lds[131072];

  const int tid = threadIdx.x;
  const int wave = tid >> 6, lane = tid & 63;
  const int wm = wave >> 2, wn = wave & 3;

  const size_t KB = (size_t)K * 2;           // global row stride bytes
  const char* Ag = (const char*)(A + (size_t)(seg + m0) * K);
  const char* Bg = (const char*)(Bt + (size_t)e * N * K + (size_t)n0 * K);

  // staging: one half = 256 rows x 64B; thread covers 16B at linear tid*16
  const int s_r  = tid >> 2;                                    // 0..127
  const int s_cb = ((tid & 3) * 16) ^ (((s_r >> 1) & 3) << 4);  // src pre-swizzle

  // stage half H_x (A and B) into unit x&3
  auto S = [&](int x) {
    const int ub = (x & 3) * 32768;
    const int kbyte = x * 64;
    const char* sa = Ag + (size_t)s_r * KB + kbyte + s_cb;
    const char* sb = Bg + (size_t)s_r * KB + kbyte + s_cb;
    __builtin_amdgcn_global_load_lds(
        (const __attribute__((address_space(1))) void*)sa,
        (__attribute__((address_space(3))) void*)(lds + ub + tid * 16), 16, 0, 0);
    __builtin_amdgcn_global_load_lds(
        (const __attribute__((address_space(1))) void*)(sa + 128 * KB),
        (__attribute__((address_space(3))) void*)(lds + ub + 8192 + tid * 16), 16, 0, 0);
    __builtin_amdgcn_global_load_lds(
        (const __attribute__((address_space(1))) void*)sb,
        (__attribute__((address_space(3))) void*)(lds + ub + 16384 + tid * 16), 16, 0, 0);
    __builtin_amdgcn_global_load_lds(
        (const __attribute__((address_space(1))) void*)(sb + 128 * KB),
        (__attribute__((address_space(3))) void*)(lds + ub + 16384 + 8192 + tid * 16), 16, 0, 0);
  };

  // fragment read offsets (swizzle folded: (row>>1)&3 == (fr>>1)&3)
  const int fr    = lane & 15;
  const int coff  = ((lane >> 4) * 16) ^ (((fr >> 1) & 3) << 4);
  const int aoff0 = (wm * 128 + fr) * 64 + coff;           // + mfrag*1024 within A-half
  const int boff0 = 16384 + (wn * 64 + fr) * 64 + coff;    // + nfrag*1024 within B-half

  f32x4 acc[8][4];
#pragma unroll
  for (int i = 0; i < 8; ++i)
#pragma unroll
    for (int j = 0; j < 4; ++j)
      acc[i][j] = (f32x4){0.f, 0.f, 0.f, 0.f};

  const int NPH = K >> 5;   // number of 32-k halves (even: K mult of 64)

  bf16x8 aE[8], bE[4], aO[8], bO[4];

#define RD(x, as, bs) {                                             \
    const char* ub_ = lds + ((x) & 3) * 32768;                      \
    _Pragma("unroll")                                               \
    for (int m_ = 0; m_ < 8; ++m_)                                  \
      as[m_] = *(const bf16x8*)(ub_ + aoff0 + m_ * 1024);           \
    _Pragma("unroll")                                               \
    for (int n_ = 0; n_ < 4; ++n_)                                  \
      bs[n_] = *(const bf16x8*)(ub_ + boff0 + n_ * 1024); }

#define MM(as, bs) {                                                \
    _Pragma("unroll")                                               \
    for (int m_ = 0; m_ < 8; ++m_)                                  \
      _Pragma("unroll")                                             \
      for (int n_ = 0; n_ < 4; ++n_)                                \
        acc[m_][n_] = __builtin_amdgcn_mfma_f32_16x16x32_bf16(      \
            as[m_], bs[n_], acc[m_][n_], 0, 0, 0); }

  // ---- prologue ("phase -1"): stage H0,H1; publish H0
  S(0); S(1);
  VMC(4);           // S(H0) landed (S(H1)'s 4 in flight)
  BARRIER();        // publish H0

  // ---- phase 0: R(H0)->E; S(H2); publish H1  (no MFMA yet)
  RD(0, aE, bE);
  S(2);
  VMC(4);           // S(H1) landed
  BARRIER();        // publish H1

  // ---- phase 1: R(H1)->O; S(H3); MFMA(H0:E); publish H2
  RD(1, aO, bO);
  S(3);
  LGKM(12);         // R(H0) complete, R(H1) in flight
  MM(aE, bE);
  VMC(4);           // S(H2) landed
  BARRIER();        // publish H2

  // ---- steady phases p=2..NPH-1 (pairs: even->E, odd->O)
  for (int p = 2; p < NPH; p += 2) {
    // even phase p: R(H_p)->E; S(H_{p+2}); MFMA(H_{p-1}:O)
    RD(p, aE, bE);
    S(p + 2 < NPH ? p + 2 : NPH - 1);
    LGKM(12);
    MM(aO, bO);
    VMC(4);
    BARRIER();
    // odd phase p+1: R(H_{p+1})->O; S(H_{p+3}); MFMA(H_p:E)
    RD(p + 1, aO, bO);
    S(p + 3 < NPH ? p + 3 : NPH - 1);
    LGKM(12);
    MM(aE, bE);
    VMC(4);
    BARRIER();
  }

  // ---- epilogue phase: MFMA(H_{NPH-1}:O)
  LGKM(0);
  MM(aO, bO);

#undef RD
#undef MM

  // ---- epilogue: C/D map col=lane&15, row=(lane>>4)*4+r  [m89-verified]
#pragma unroll
  for (int mf = 0; mf < 8; ++mf) {
#pragma unroll
    for (int r2 = 0; r2 < 4; ++r2) {
      const int gm = m0 + wm * 128 + mf * 16 + (lane >> 4) * 4 + r2;
      if (gm >= cnt) continue;
      if (SCATTER) {
        const int s = seg + gm;
        const float g = gate_slot[s];
        const int tk = tok_k[s];
        float* dst = (float*)Cout + ((size_t)(tk & 1) * TOK + (size_t)(tk >> 1)) * EMB;
#pragma unroll
        for (int nf = 0; nf < 4; ++nf) {
          const int gcol = n0 + wn * 64 + nf * 16 + fr;
          dst[gcol] = g * (acc[mf][nf][r2] + bias[(size_t)e * N + gcol]);
        }
      } else {
#pragma unroll
        for (int nf = 0; nf < 4; ++nf) {
          const int gcol = n0 + wn * 64 + nf * 16 + fr;
          float v = acc[mf][nf][r2] + bias[(size_t)e * N + gcol];
          if (GELU) v = 0.5f * v * (1.0f + erff(v * 0.70710678118654752f));
          if (OUTBF)
            ((__hip_bfloat16*)Cout)[(size_t)(seg + gm) * N + gcol] = __float2bfloat16(v);
          else
            ((float*)Cout)[(size_t)(seg + gm) * N + gcol] = v;
        }
      }
    }
  }
}

// out = y0 + y1 (token-indexed, fully coalesced)
__global__ __launch_bounds__(256) void k_combine2(const float* __restrict__ ybuf2,
                                                  float* __restrict__ out)
{
  const size_t total = (size_t)TOK * EMB / 4;
  for (size_t i = blockIdx.x * 256 + threadIdx.x; i < total; i += (size_t)gridDim.x * 256) {
    const float4 a = ((const float4*)ybuf2)[i];
    const float4 b = ((const float4*)(ybuf2 + (size_t)TOK * EMB))[i];
    float4 o;
    o.x = a.x + b.x; o.y = a.y + b.y; o.z = a.z + b.z; o.w = a.w + b.w;
    ((float4*)out)[i] = o;
  }
}

// ---------------- launch ----------------

extern "C" void kernel_launch(void* const* d_in, const int* in_sizes, int n_in,
                              void* d_out, int out_size, void* d_ws, size_t ws_size,
                              hipStream_t stream)
{
  const float* x  = (const float*)d_in[0];
  const float* Wg = (const float*)d_in[1];
  const float* bg = (const float*)d_in[2];
  const float* W1 = (const float*)d_in[3];
  const float* b1 = (const float*)d_in[4];
  const float* W2 = (const float*)d_in[5];
  const float* b2 = (const float*)d_in[6];
  const float* W3 = (const float*)d_in[7];
  const float* b3 = (const float*)d_in[8];
  float* out = (float*)d_out;

  char* ws = (char*)d_ws;
  size_t off = 0;
  auto alloc = [&](size_t bytes) -> void* {
    void* p = ws + off;
    off = (off + bytes + 255) & ~(size_t)255;
    return p;
  };

  int*   counts    = (int*)alloc(NE * 4);
  int*   fill      = (int*)alloc(NE * 4);
  int*   offsets   = (int*)alloc((NE + 1) * 4);
  int*   tmap      = (int*)alloc(MAXTILES * 4);
  int*   eidx      = (int*)alloc((size_t)TOK * 2 * 4);
  float* gates     = (float*)alloc((size_t)TOK * 2 * 4);
  int*   route_tok = (int*)alloc((size_t)SLOTS * 4);
  float* gate_slot = (float*)alloc((size_t)(SLOTS + SLACK) * 4);
  int*   tok_k     = (int*)alloc((size_t)(SLOTS + SLACK) * 4);
  __hip_bfloat16* Wb1 = (__hip_bfloat16*)alloc((size_t)NE * EMB  * HID  * 2);
  __hip_bfloat16* Wb2 = (__hip_bfloat16*)alloc((size_t)NE * HID  * HID2 * 2);
  __hip_bfloat16* Wb3 = (__hip_bfloat16*)alloc((size_t)NE * HID2 * EMB  * 2);
  __hip_bfloat16* xg  = (__hip_bfloat16*)alloc((size_t)(SLOTS + SLACK) * EMB  * 2);
  __hip_bfloat16* h1  = (__hip_bfloat16*)alloc((size_t)(SLOTS + SLACK) * HID  * 2);
  __hip_bfloat16* h2  = (__hip_bfloat16*)alloc((size_t)(SLOTS + SLACK) * HID2 * 2);
  float*          ybuf2 = (float*)alloc((size_t)2 * TOK * EMB * 4);
  (void)ws_size; (void)in_sizes; (void)n_in; (void)out_size;

  k_init<<<1, 64, 0, stream>>>(counts, fill);
  k_gating<<<TOK / 4, 256, 0, stream>>>(x, Wg, bg, eidx, gates);
  k_count<<<SLOTS / 512, 256, 0, stream>>>(eidx, counts);
  k_offsets<<<1, 1, 0, stream>>>(counts, offsets, tmap);
  k_route<<<TOK / 256, 256, 0, stream>>>(eidx, fill, offsets, route_tok,
                                         gate_slot, tok_k, gates);
  k_gather<<<SLOTS / 4, 256, 0, stream>>>(x, route_tok, xg);

  k_transpose_all<<<NT1 + NT2 + NT3, dim3(32, 8), 0, stream>>>(W1, W2, W3, Wb1, Wb2, Wb3);

  ffn_gemm8<true,  true,  false><<<dim3(HID  / 256, MAXTILES), 512, 0, stream>>>(
      xg, Wb1, b1, h1, counts, offsets, tmap, nullptr, nullptr, EMB,  HID);
  ffn_gemm8<true,  true,  false><<<dim3(HID2 / 256, MAXTILES), 512, 0, stream>>>(
      h1, Wb2, b2, h2, counts, offsets, tmap, nullptr, nullptr, HID,  HID2);
  ffn_gemm8<false, false, true ><<<dim3(EMB  / 256, MAXTILES), 512, 0, stream>>>(
      h2, Wb3, b3, ybuf2, counts, offsets, tmap, gate_slot, tok_k, HID2, EMB);

  k_combine2<<<2048, 256, 0, stream>>>(ybuf2, out);
}